// Round 3
// baseline (1146.107 us; speedup 1.0000x reference)
//
#include <hip/hip_runtime.h>

// C3 partial conv: x[64,6,256,256] f32, W[16,6,5,5] f32 (sparse connection table
// handled by iterating connected channels only), b[16]. out[64,16,252,252] f32.
// out = 1.7159 * tanh((2/3) * (conv_valid(x, W) + b))
//
// Round 6: arithmetic-intensity attack. Round 5 (2 rows/thread, VGPR=96,
// 5 waves/SIMD) is still latency-bound: real VALU util ~18% (the 73% counter
// is a gfx94x-fallback formula over-reporting 4x), FMA floor 80us vs 470us
// measured. Dominant stalls: weight s_loads (1 per 2 FMAs) + window ds_reads.
// This round: 4 output rows/thread (32x32 tile, 256 threads) -> each weight
// feeds 4 independent FMAs (2x reuse, ILP hides load latency), window reads
// per FMA drop 0.12->0.08, loop/staging overhead per output halves.
// Channel split (2 groups of 8) kept: acc[8][4]=32 + win[8][5]=40 live regs.
// NO min-waves launch_bounds arg (hard VGPR clamp -> scratch disaster, r2/r4).

__global__ __launch_bounds__(256) void c3_partial_conv_kernel(
    const float* __restrict__ x,   // [64,6,256,256]
    const float* __restrict__ W,   // [16,6,5,5]
    const float* __restrict__ b,   // [16]
    float* __restrict__ out)       // [64,16,252,252]
{
    // Reverse maps per group: for input channel c, the output channels in
    // this group that consume it (count arrays give real lengths).
    constexpr int G0N[6] = {4, 5, 5, 5, 4, 3};
    constexpr int G0O[6][5] = {
        {0, 4, 5, 6, 0},
        {0, 1, 5, 6, 7},
        {0, 1, 2, 6, 7},
        {1, 2, 3, 6, 7},
        {2, 3, 4, 7, 0},
        {3, 4, 5, 0, 0}};
    constexpr int G1N[6] = {6, 5, 5, 5, 6, 7};
    constexpr int G1O[6][7] = {
        {9, 10, 11, 12, 14, 15, 8},
        {10, 11, 12, 13, 15, 8, 8},
        {8, 11, 13, 14, 15, 8, 8},
        {8, 9, 12, 14, 15, 8, 8},
        {8, 9, 10, 12, 13, 15, 8},
        {8, 9, 10, 11, 13, 14, 15}};

    // Input tile: 6 ch x 36 rows x 36 cols (row stride 40 floats, 16B-aligned).
    __shared__ float lds[6][36][40];  // 34560 B -> 4 blocks/CU

    const int tx  = threadIdx.x;   // 0..31 -> output col within tile
    const int ty  = threadIdx.y;   // 0..7  -> output row quad
    const int tid = ty * 32 + tx;

    const int tileX = blockIdx.x << 5;   // 0..224
    const int tileY = blockIdx.y << 5;   // 0..224
    const int batch = blockIdx.z;

    const float* xb = x + (size_t)batch * 6 * 256 * 256;

    // ---- stage input tile: float4 chunks. 6*36*9 = 1944 chunks ----
    for (int i = tid; i < 1944; i += 256) {
        int c   = i / 324;            // 36 rows * 9 chunks
        int rem = i - c * 324;
        int r   = rem / 9;
        int q   = rem - r * 9;
        int gr  = tileY + r;
        int gc0 = tileX + (q << 2);
        float4 v = make_float4(0.f, 0.f, 0.f, 0.f);
        if (gr < 256 && gc0 < 256)    // chunk fully in-bounds or fully out
            v = *reinterpret_cast<const float4*>(&xb[(c * 256 + gr) * 256 + gc0]);
        *reinterpret_cast<float4*>(&lds[c][r][q << 2]) = v;
    }
    __syncthreads();

    const int row0 = ty << 2;            // local output row base (0..28)
    const int ocol = tileX + tx;
    float* ob = out + (size_t)batch * 16 * 252 * 252;
    const bool colok = (ocol < 252);

    // ================= group 0 : out channels 0..7 =================
    {
        float acc[8][4];
        #pragma unroll
        for (int o = 0; o < 8; ++o) {
            float bv = b[o];
            #pragma unroll
            for (int dy = 0; dy < 4; ++dy) acc[o][dy] = bv;
        }

        #pragma unroll
        for (int c = 0; c < 6; ++c) {
            float win[8][5];
            #pragma unroll
            for (int r = 0; r < 8; ++r)
                #pragma unroll
                for (int j = 0; j < 5; ++j)
                    win[r][j] = lds[c][row0 + r][tx + j];

            #pragma unroll
            for (int oi = 0; oi < G0N[c]; ++oi) {
                const int o = G0O[c][oi];
                const float* wp = W + (o * 6 + c) * 25;
                #pragma unroll
                for (int ky = 0; ky < 5; ++ky)
                    #pragma unroll
                    for (int kx = 0; kx < 5; ++kx) {
                        const float wv = wp[ky * 5 + kx];   // uniform -> s_load
                        #pragma unroll
                        for (int dy = 0; dy < 4; ++dy)
                            acc[o][dy] = fmaf(win[ky + dy][kx], wv, acc[o][dy]);
                    }
            }
        }

        if (colok) {
            #pragma unroll
            for (int o = 0; o < 8; ++o)
                #pragma unroll
                for (int dy = 0; dy < 4; ++dy) {
                    int orow = tileY + row0 + dy;
                    if (orow < 252) {
                        float z = acc[o][dy] * (2.0f / 3.0f);
                        float e = __expf(2.0f * z);              // v_exp_f32 path
                        float rr = __builtin_amdgcn_rcpf(e + 1.0f);
                        ob[(o * 252 + orow) * 252 + ocol] = 1.7159f * (1.0f - 2.0f * rr);
                    }
                }
        }
    }

    // keep the two groups' live ranges separate (don't let the scheduler
    // hoist group-1 window loads above group-0 epilogue)
    __builtin_amdgcn_sched_barrier(0);

    // ================= group 1 : out channels 8..15 =================
    {
        float acc[8][4];
        #pragma unroll
        for (int o = 0; o < 8; ++o) {
            float bv = b[8 + o];
            #pragma unroll
            for (int dy = 0; dy < 4; ++dy) acc[o][dy] = bv;
        }

        #pragma unroll
        for (int c = 0; c < 6; ++c) {
            float win[8][5];
            #pragma unroll
            for (int r = 0; r < 8; ++r)
                #pragma unroll
                for (int j = 0; j < 5; ++j)
                    win[r][j] = lds[c][row0 + r][tx + j];

            #pragma unroll
            for (int oi = 0; oi < G1N[c]; ++oi) {
                const int o = G1O[c][oi];            // 8..15, compile-time
                const float* wp = W + (o * 6 + c) * 25;
                #pragma unroll
                for (int ky = 0; ky < 5; ++ky)
                    #pragma unroll
                    for (int kx = 0; kx < 5; ++kx) {
                        const float wv = wp[ky * 5 + kx];
                        #pragma unroll
                        for (int dy = 0; dy < 4; ++dy)
                            acc[o - 8][dy] = fmaf(win[ky + dy][kx], wv, acc[o - 8][dy]);
                    }
            }
        }

        if (colok) {
            #pragma unroll
            for (int o = 0; o < 8; ++o)
                #pragma unroll
                for (int dy = 0; dy < 4; ++dy) {
                    int orow = tileY + row0 + dy;
                    if (orow < 252) {
                        float z = acc[o][dy] * (2.0f / 3.0f);
                        float e = __expf(2.0f * z);
                        float rr = __builtin_amdgcn_rcpf(e + 1.0f);
                        ob[((8 + o) * 252 + orow) * 252 + ocol] = 1.7159f * (1.0f - 2.0f * rr);
                    }
                }
        }
    }
}

extern "C" void kernel_launch(void* const* d_in, const int* in_sizes, int n_in,
                              void* d_out, int out_size, void* d_ws, size_t ws_size,
                              hipStream_t stream) {
    const float* x = (const float*)d_in[0];
    const float* W = (const float*)d_in[1];
    const float* b = (const float*)d_in[2];
    float* out = (float*)d_out;

    dim3 grid(8, 8, 64);   // 8 col-tiles x 8 row-tiles x 64 batches
    dim3 block(32, 8);
    hipLaunchKernelGGL(c3_partial_conv_kernel, grid, block, 0, stream, x, W, b, out);
}

// Round 4
// 241.260 us; speedup vs baseline: 4.7505x; 4.7505x over previous
//
#include <hip/hip_runtime.h>

// C3 partial conv: x[64,6,256,256] f32, W[16,6,5,5] f32 (sparse connection table
// handled by iterating connected channels only), b[16]. out[64,16,252,252] f32.
// out = 1.7159 * tanh((2/3) * (conv_valid(x, W) + b))
//
// Round 7: instruction-footprint attack. Evidence: r5 (≈35KB straight-line
// code) and r6 (≈75KB) have same occupancy / clean memory counters, but r6 is
// 2.2x slower with VALUBusy FALLING 73->29 -- consistent with L1I (32KB)
// thrash; I-fetch misses go to L2 so they never show in FETCH_SIZE. Also
// explains why 2.5x occupancy (r3->r5) bought only 1.18x: per-CU fetch is a
// shared bottleneck.
// Fix: EXACT r5 structure (32x16 tile, 2 rows/thread, 20-row LDS, 2 groups
// of 8 channels), but the (c, out-channel) iteration is ROLLED at runtime
// with a uniform scalar switch into 16 static 50-FMA blocks (~10KB hot code,
// fits L1I). Accumulators stay statically indexed (runtime-indexed arrays
// spill to scratch). Same FMA/ds_read/s_load counts as r5.
// NO min-waves launch_bounds arg (hard VGPR clamp -> scratch disaster, r2/r4).

__device__ __forceinline__ void conv25(const float* __restrict__ wp,
                                       const float (&win)[6][5],
                                       float& a0, float& a1) {
    #pragma unroll
    for (int ky = 0; ky < 5; ++ky)
        #pragma unroll
        for (int kx = 0; kx < 5; ++kx) {
            const float wv = wp[ky * 5 + kx];   // uniform -> s_load batch
            a0 = fmaf(win[ky + 0][kx], wv, a0);
            a1 = fmaf(win[ky + 1][kx], wv, a1);
        }
}

__global__ __launch_bounds__(256) void c3_partial_conv_kernel(
    const float* __restrict__ x,   // [64,6,256,256]
    const float* __restrict__ W,   // [16,6,5,5]
    const float* __restrict__ b,   // [16]
    float* __restrict__ out)       // [64,16,252,252]
{
    // Reverse maps per group: for input channel c, the output channels in
    // this group that consume it (count arrays give real lengths).
    constexpr int G0N[6] = {4, 5, 5, 5, 4, 3};
    constexpr int G0O[6][5] = {
        {0, 4, 5, 6, 0},
        {0, 1, 5, 6, 7},
        {0, 1, 2, 6, 7},
        {1, 2, 3, 6, 7},
        {2, 3, 4, 7, 0},
        {3, 4, 5, 0, 0}};
    constexpr int G1N[6] = {6, 5, 5, 5, 6, 7};
    constexpr int G1O[6][7] = {
        {9, 10, 11, 12, 14, 15, 8},
        {10, 11, 12, 13, 15, 8, 8},
        {8, 11, 13, 14, 15, 8, 8},
        {8, 9, 12, 14, 15, 8, 8},
        {8, 9, 10, 12, 13, 15, 8},
        {8, 9, 10, 11, 13, 14, 15}};

    // Input tile: 6 ch x 20 rows x 36 cols (row stride 40 floats, 16B-aligned).
    __shared__ float lds[6][20][40];  // 19200 B

    const int tx  = threadIdx.x;   // 0..31 -> output col within tile
    const int ty  = threadIdx.y;   // 0..7  -> output row pair
    const int tid = ty * 32 + tx;

    const int tileX = blockIdx.x << 5;   // 0..224
    const int tileY = blockIdx.y << 4;   // 0..240
    const int batch = blockIdx.z;

    const float* xb = x + (size_t)batch * 6 * 256 * 256;

    // ---- stage input tile: float4 chunks. 6*20*9 = 1080 chunks ----
    for (int i = tid; i < 1080; i += 256) {
        int c   = i / 180;
        int rem = i - c * 180;
        int r   = rem / 9;
        int q   = rem - r * 9;
        int gr  = tileY + r;
        int gc0 = tileX + (q << 2);
        float4 v = make_float4(0.f, 0.f, 0.f, 0.f);
        if (gr < 256 && gc0 < 256)    // chunk fully in-bounds or fully out
            v = *reinterpret_cast<const float4*>(&xb[(c * 256 + gr) * 256 + gc0]);
        *reinterpret_cast<float4*>(&lds[c][r][q << 2]) = v;
    }
    __syncthreads();

    const int row0 = ty << 1;            // local output row base (0..14)
    const int ocol = tileX + tx;
    float* ob = out + (size_t)batch * 16 * 252 * 252;
    const bool colok = (ocol < 252);

    // ================= group 0 : out channels 0..7 =================
    {
        float acc[8][2];
        #pragma unroll
        for (int o = 0; o < 8; ++o) {
            float bv = b[o];
            acc[o][0] = bv; acc[o][1] = bv;
        }

        #pragma unroll 1
        for (int c = 0; c < 6; ++c) {
            float win[6][5];
            #pragma unroll
            for (int r = 0; r < 6; ++r)
                #pragma unroll
                for (int j = 0; j < 5; ++j)
                    win[r][j] = lds[c][row0 + r][tx + j];

            const int n = G0N[c];
            #pragma unroll 1
            for (int oi = 0; oi < n; ++oi) {
                switch (G0O[c][oi]) {      // uniform scalar branch
                    case 0: conv25(W + (0 * 6 + c) * 25, win, acc[0][0], acc[0][1]); break;
                    case 1: conv25(W + (1 * 6 + c) * 25, win, acc[1][0], acc[1][1]); break;
                    case 2: conv25(W + (2 * 6 + c) * 25, win, acc[2][0], acc[2][1]); break;
                    case 3: conv25(W + (3 * 6 + c) * 25, win, acc[3][0], acc[3][1]); break;
                    case 4: conv25(W + (4 * 6 + c) * 25, win, acc[4][0], acc[4][1]); break;
                    case 5: conv25(W + (5 * 6 + c) * 25, win, acc[5][0], acc[5][1]); break;
                    case 6: conv25(W + (6 * 6 + c) * 25, win, acc[6][0], acc[6][1]); break;
                    case 7: conv25(W + (7 * 6 + c) * 25, win, acc[7][0], acc[7][1]); break;
                    default: break;
                }
            }
        }

        if (colok) {
            #pragma unroll
            for (int o = 0; o < 8; ++o)
                #pragma unroll
                for (int dy = 0; dy < 2; ++dy) {
                    int orow = tileY + row0 + dy;
                    if (orow < 252) {
                        float z = acc[o][dy] * (2.0f / 3.0f);
                        float e = __expf(2.0f * z);              // v_exp_f32 path
                        float rr = __builtin_amdgcn_rcpf(e + 1.0f);
                        ob[(o * 252 + orow) * 252 + ocol] = 1.7159f * (1.0f - 2.0f * rr);
                    }
                }
        }
    }

    // keep the two groups' live ranges separate
    __builtin_amdgcn_sched_barrier(0);

    // ================= group 1 : out channels 8..15 =================
    {
        float acc[8][2];
        #pragma unroll
        for (int o = 0; o < 8; ++o) {
            float bv = b[8 + o];
            acc[o][0] = bv; acc[o][1] = bv;
        }

        #pragma unroll 1
        for (int c = 0; c < 6; ++c) {
            float win[6][5];
            #pragma unroll
            for (int r = 0; r < 6; ++r)
                #pragma unroll
                for (int j = 0; j < 5; ++j)
                    win[r][j] = lds[c][row0 + r][tx + j];

            const int n = G1N[c];
            #pragma unroll 1
            for (int oi = 0; oi < n; ++oi) {
                switch (G1O[c][oi]) {      // uniform scalar branch
                    case  8: conv25(W + ( 8 * 6 + c) * 25, win, acc[0][0], acc[0][1]); break;
                    case  9: conv25(W + ( 9 * 6 + c) * 25, win, acc[1][0], acc[1][1]); break;
                    case 10: conv25(W + (10 * 6 + c) * 25, win, acc[2][0], acc[2][1]); break;
                    case 11: conv25(W + (11 * 6 + c) * 25, win, acc[3][0], acc[3][1]); break;
                    case 12: conv25(W + (12 * 6 + c) * 25, win, acc[4][0], acc[4][1]); break;
                    case 13: conv25(W + (13 * 6 + c) * 25, win, acc[5][0], acc[5][1]); break;
                    case 14: conv25(W + (14 * 6 + c) * 25, win, acc[6][0], acc[6][1]); break;
                    case 15: conv25(W + (15 * 6 + c) * 25, win, acc[7][0], acc[7][1]); break;
                    default: break;
                }
            }
        }

        if (colok) {
            #pragma unroll
            for (int o = 0; o < 8; ++o)
                #pragma unroll
                for (int dy = 0; dy < 2; ++dy) {
                    int orow = tileY + row0 + dy;
                    if (orow < 252) {
                        float z = acc[o][dy] * (2.0f / 3.0f);
                        float e = __expf(2.0f * z);
                        float rr = __builtin_amdgcn_rcpf(e + 1.0f);
                        ob[((8 + o) * 252 + orow) * 252 + ocol] = 1.7159f * (1.0f - 2.0f * rr);
                    }
                }
        }
    }
}

extern "C" void kernel_launch(void* const* d_in, const int* in_sizes, int n_in,
                              void* d_out, int out_size, void* d_ws, size_t ws_size,
                              hipStream_t stream) {
    const float* x = (const float*)d_in[0];
    const float* W = (const float*)d_in[1];
    const float* b = (const float*)d_in[2];
    float* out = (float*)d_out;

    dim3 grid(8, 16, 64);   // 8 col-tiles x 16 row-tiles x 64 batches
    dim3 block(32, 8);
    hipLaunchKernelGGL(c3_partial_conv_kernel, grid, block, 0, stream, x, W, b, out);
}